// Round 4
// baseline (371.836 us; speedup 1.0000x reference)
//
#include <hip/hip_runtime.h>

// StaticGNN: 2-layer GCN. N=50000, E=800000, D=128, fp32.
// out = relu( D^{-1/2}(A+I)D^{-1/2} (X W_l) + b_l ), stacked twice.

#define D 128
#define D4 32   // D/4 float4s per row
#define D2 64   // D/2 float2s per row
#define SCAN_B 256

// ---------------- setup kernels ----------------

// degInt starts zeroed (memset); counts in-edges only; deg = count + 1 (self-loop).
__global__ void count_kernel(const int* __restrict__ dst, int* degInt, int e) {
    int i = blockIdx.x * blockDim.x + threadIdx.x;
    if (i < e) atomicAdd(&degInt[dst[i]], 1);
}

// Phase A: per-block sums of degInt (256 elements per block).
__global__ __launch_bounds__(SCAN_B) void scanA_kernel(const int* __restrict__ degInt,
                                                       int* __restrict__ partial, int n) {
    __shared__ int red[SCAN_B / 64];
    int tid = threadIdx.x;
    int i = blockIdx.x * SCAN_B + tid;
    int c = (i < n) ? degInt[i] : 0;
    int s = c;
    for (int off = 32; off > 0; off >>= 1) s += __shfl_down(s, off, 64);
    if ((tid & 63) == 0) red[tid >> 6] = s;
    __syncthreads();
    if (tid == 0) {
        int t = 0;
#pragma unroll
        for (int w = 0; w < SCAN_B / 64; ++w) t += red[w];
        partial[blockIdx.x] = t;
    }
}

// Phase B: single block scans nb partials -> blockoff (exclusive), blockoff[nb]=total.
__global__ __launch_bounds__(256) void scanB_kernel(const int* __restrict__ partial,
                                                    int* __restrict__ blockoff, int nb) {
    __shared__ int sc[256];
    int tid = threadIdx.x;
    int c = (tid < nb) ? partial[tid] : 0;
    sc[tid] = c;
    __syncthreads();
    for (int off = 1; off < 256; off <<= 1) {
        int v = (tid >= off) ? sc[tid - off] : 0;
        __syncthreads();
        sc[tid] += v;
        __syncthreads();
    }
    if (tid <= nb) blockoff[tid] = (tid == 0) ? 0 : sc[tid - 1];
}

// Phase C: per-block exclusive scan + global base -> row_ptr; fused dinv.
__global__ __launch_bounds__(SCAN_B) void scanC_kernel(const int* __restrict__ degInt,
                                                       const int* __restrict__ blockoff,
                                                       int* __restrict__ row_ptr,
                                                       float* __restrict__ dinv,
                                                       int n, int nb) {
    __shared__ int sc[SCAN_B];
    int tid = threadIdx.x;
    int i = blockIdx.x * SCAN_B + tid;
    int c = (i < n) ? degInt[i] : 0;
    sc[tid] = c;
    __syncthreads();
    for (int off = 1; off < SCAN_B; off <<= 1) {
        int v = (tid >= off) ? sc[tid - off] : 0;
        __syncthreads();
        sc[tid] += v;
        __syncthreads();
    }
    if (i < n) {
        int excl = sc[tid] - c;
        row_ptr[i] = blockoff[blockIdx.x] + excl;
        dinv[i] = rsqrtf((float)(c + 1));
    }
    if (blockIdx.x == 0 && tid == 0) row_ptr[n] = blockoff[nb];  // total = E
}

__global__ void fill_kernel(const int* __restrict__ src, const int* __restrict__ dst,
                            const int* __restrict__ row_ptr, int* cursor,
                            const float* __restrict__ dinv,
                            int* __restrict__ col, float* __restrict__ coefv, int e) {
    int i = blockIdx.x * blockDim.x + threadIdx.x;
    if (i < e) {
        int d = dst[i];
        int s = src[i];
        int pos = row_ptr[d] + atomicAdd(&cursor[d], 1);
        col[pos] = s;
        coefv[pos] = dinv[s] * dinv[d];
    }
}

// ---------------- GEMM: H[n x 128] = X[n x 128] @ W[128 x 128] ----------------

__global__ __launch_bounds__(256) void gemm_kernel(const float* __restrict__ X,
                                                   const float* __restrict__ W,
                                                   float* __restrict__ H, int n) {
    __shared__ float xs[64 * 128];  // 32 KB
    const int row0 = blockIdx.x * 64;
    const int tid = threadIdx.x;

    const float4* X4 = (const float4*)X;
    float4* xs4 = (float4*)xs;
#pragma unroll
    for (int q = 0; q < 8; ++q) {
        int idx = tid + q * 256;          // 0..2047
        int r = idx >> 5;                 // tile row
        int c4 = idx & 31;                // float4 col
        int gr = row0 + r; if (gr >= n) gr = n - 1;
        xs4[idx] = X4[gr * D4 + c4];
    }
    __syncthreads();

    const int tx = tid & 31;
    const int ty = tid >> 5;
    float4 acc[8];
#pragma unroll
    for (int i = 0; i < 8; ++i) acc[i] = make_float4(0.f, 0.f, 0.f, 0.f);

    const float4* W4 = (const float4*)W;
    for (int k4 = 0; k4 < 32; ++k4) {
        float4 a[8];
#pragma unroll
        for (int i = 0; i < 8; ++i) a[i] = xs4[(ty * 8 + i) * 32 + k4];
#pragma unroll
        for (int kk = 0; kk < 4; ++kk) {
            float4 w = W4[(k4 * 4 + kk) * 32 + tx];
#pragma unroll
            for (int i = 0; i < 8; ++i) {
                float av = (kk == 0) ? a[i].x : (kk == 1) ? a[i].y : (kk == 2) ? a[i].z : a[i].w;
                acc[i].x = fmaf(av, w.x, acc[i].x);
                acc[i].y = fmaf(av, w.y, acc[i].y);
                acc[i].z = fmaf(av, w.z, acc[i].z);
                acc[i].w = fmaf(av, w.w, acc[i].w);
            }
        }
    }

    float4* H4 = (float4*)H;
#pragma unroll
    for (int i = 0; i < 8; ++i) {
        int r = row0 + ty * 8 + i;
        if (r < n) H4[r * D4 + tx] = acc[i];
    }
}

// ---------------- Aggregation ----------------
// Y[v] = relu( sum_{e->v} coef*H[src] + dinv[v]^2 * H[v] + b )
// One wave per node, lane owns a float2. Batch-16 gathers; tail handled as a
// MASKED batch (wave-uniform guards) so no serial dependent-gather tail.

#define AB 16

__global__ __launch_bounds__(256) void agg_kernel(const float* __restrict__ H,
                                                  const int* __restrict__ col,
                                                  const float* __restrict__ coefv,
                                                  const int* __restrict__ row_ptr,
                                                  const float* __restrict__ dinv,
                                                  const float* __restrict__ bias,
                                                  float* __restrict__ Y, int n) {
    int wave = threadIdx.x >> 6;
    int lane = threadIdx.x & 63;
    int v = blockIdx.x * 4 + wave;
    if (v >= n) return;

    const float2* H2 = (const float2*)H;
    float di = dinv[v];
    float selfc = di * di;
    float2 hv = H2[(size_t)v * D2 + lane];
    float ax = hv.x * selfc;
    float ay = hv.y * selfc;

    int e0 = row_ptr[v];
    int e1 = row_ptr[v + 1];
    int e = e0;
    // full batches of AB
    for (; e + AB <= e1; e += AB) {
        int s[AB]; float c[AB]; float2 hs[AB];
#pragma unroll
        for (int j = 0; j < AB; ++j) { s[j] = col[e + j]; c[j] = coefv[e + j]; }
#pragma unroll
        for (int j = 0; j < AB; ++j) hs[j] = H2[(size_t)s[j] * D2 + lane];
#pragma unroll
        for (int j = 0; j < AB; ++j) {
            ax = fmaf(hs[j].x, c[j], ax);
            ay = fmaf(hs[j].y, c[j], ay);
        }
    }
    // masked tail batch: all loads issue before any use (uniform branches)
    if (e < e1) {
        int m = e1 - e;
        float c[AB]; float2 hs[AB];
#pragma unroll
        for (int j = 0; j < AB; ++j) {
            if (j < m) {
                int s = col[e + j];
                c[j] = coefv[e + j];
                hs[j] = H2[(size_t)s * D2 + lane];
            }
        }
#pragma unroll
        for (int j = 0; j < AB; ++j) {
            if (j < m) {
                ax = fmaf(hs[j].x, c[j], ax);
                ay = fmaf(hs[j].y, c[j], ay);
            }
        }
    }
    float2 bv = ((const float2*)bias)[lane];
    float ox = ax + bv.x;
    float oy = ay + bv.y;
    ox = ox > 0.f ? ox : 0.f;
    oy = oy > 0.f ? oy : 0.f;
    ((float2*)Y)[(size_t)v * D2 + lane] = make_float2(ox, oy);
}

// ---------------- launch ----------------

extern "C" void kernel_launch(void* const* d_in, const int* in_sizes, int n_in,
                              void* d_out, int out_size, void* d_ws, size_t ws_size,
                              hipStream_t stream) {
    const float* x = (const float*)d_in[0];
    const int* ei = (const int*)d_in[1];
    const float* W = (const float*)d_in[2];
    const float* b = (const float*)d_in[3];
    float* out = (float*)d_out;

    const int N = in_sizes[0] / D;       // 50000
    const int E = in_sizes[1] / 2;       // 800000

    const int* src = ei;
    const int* dst = ei + E;

    int* wsi = (int*)d_ws;
    float* wsf = (float*)d_ws;
    const size_t o_deg    = 0;               // N ints (zeroed)
    const size_t o_cursor = o_deg + 50000;   // N ints (zeroed)
    const size_t o_dinv   = o_cursor + 50000;// N floats
    const size_t o_rp     = o_dinv + 50000;  // N+1 ints (pad to 50016)
    const size_t o_part   = o_rp + 50016;    // 256 ints
    const size_t o_boff   = o_part + 256;    // 256 ints
    const size_t o_col    = o_boff + 256;    // E ints
    const size_t o_coef   = o_col + 800000;  // E floats
    const size_t o_h      = o_coef + 800000; // N*D floats
    const size_t o_y1     = o_h + 6400000;   // N*D floats

    int* degInt  = wsi + o_deg;
    int* cursor  = wsi + o_cursor;
    float* dinv  = wsf + o_dinv;
    int* row_ptr = wsi + o_rp;
    int* partial = wsi + o_part;
    int* blockoff= wsi + o_boff;
    int* col     = wsi + o_col;
    float* coefv = wsf + o_coef;
    float* h     = wsf + o_h;
    float* y1    = wsf + o_y1;

    const int nb_e = (E + 255) / 256;           // 3125
    const int nb_s = (N + SCAN_B - 1) / SCAN_B; // 196

    hipMemsetAsync(degInt, 0, (size_t)2 * 50000 * sizeof(int), stream);  // deg + cursor
    count_kernel<<<nb_e, 256, 0, stream>>>(dst, degInt, E);
    scanA_kernel<<<nb_s, SCAN_B, 0, stream>>>(degInt, partial, N);
    scanB_kernel<<<1, 256, 0, stream>>>(partial, blockoff, nb_s);
    scanC_kernel<<<nb_s, SCAN_B, 0, stream>>>(degInt, blockoff, row_ptr, dinv, N, nb_s);
    fill_kernel<<<nb_e, 256, 0, stream>>>(src, dst, row_ptr, cursor, dinv, col, coefv, E);

    const int nb_gemm = (N + 63) / 64;   // 782
    const int nb_agg  = (N + 3) / 4;     // 12500

    gemm_kernel<<<nb_gemm, 256, 0, stream>>>(x, W, h, N);
    agg_kernel<<<nb_agg, 256, 0, stream>>>(h, col, coefv, row_ptr, dinv, b, y1, N);
    gemm_kernel<<<nb_gemm, 256, 0, stream>>>(y1, W + D * D, h, N);
    agg_kernel<<<nb_agg, 256, 0, stream>>>(h, col, coefv, row_ptr, dinv, b + D, out, N);
}

// Round 5
// 312.922 us; speedup vs baseline: 1.1883x; 1.1883x over previous
//
#include <hip/hip_runtime.h>
#include <hip/hip_fp16.h>

// StaticGNN: 2-layer GCN. N=50000, E=800000, D=128, fp32 in/out.
// out = relu( D^{-1/2}(A+I)D^{-1/2} (X W_l) + b_l ), stacked twice.
// H (the per-layer X@W result) is stored fp16 to halve the random-gather bytes.

#define D 128
#define D4 32    // D/4 float4s per fp32 row
#define DH2 64  // D/2 half2 (uint) per fp16 row
#define SCAN_B 256

// ---------------- setup kernels ----------------

__global__ void count_kernel(const int* __restrict__ dst, int* degInt, int e) {
    int i = blockIdx.x * blockDim.x + threadIdx.x;
    if (i < e) atomicAdd(&degInt[dst[i]], 1);
}

__global__ __launch_bounds__(SCAN_B) void scanA_kernel(const int* __restrict__ degInt,
                                                       int* __restrict__ partial, int n) {
    __shared__ int red[SCAN_B / 64];
    int tid = threadIdx.x;
    int i = blockIdx.x * SCAN_B + tid;
    int c = (i < n) ? degInt[i] : 0;
    int s = c;
    for (int off = 32; off > 0; off >>= 1) s += __shfl_down(s, off, 64);
    if ((tid & 63) == 0) red[tid >> 6] = s;
    __syncthreads();
    if (tid == 0) {
        int t = 0;
#pragma unroll
        for (int w = 0; w < SCAN_B / 64; ++w) t += red[w];
        partial[blockIdx.x] = t;
    }
}

__global__ __launch_bounds__(256) void scanB_kernel(const int* __restrict__ partial,
                                                    int* __restrict__ blockoff, int nb) {
    __shared__ int sc[256];
    int tid = threadIdx.x;
    int c = (tid < nb) ? partial[tid] : 0;
    sc[tid] = c;
    __syncthreads();
    for (int off = 1; off < 256; off <<= 1) {
        int v = (tid >= off) ? sc[tid - off] : 0;
        __syncthreads();
        sc[tid] += v;
        __syncthreads();
    }
    if (tid <= nb) blockoff[tid] = (tid == 0) ? 0 : sc[tid - 1];
}

__global__ __launch_bounds__(SCAN_B) void scanC_kernel(const int* __restrict__ degInt,
                                                       const int* __restrict__ blockoff,
                                                       int* __restrict__ row_ptr,
                                                       float* __restrict__ dinv,
                                                       int n, int nb) {
    __shared__ int sc[SCAN_B];
    int tid = threadIdx.x;
    int i = blockIdx.x * SCAN_B + tid;
    int c = (i < n) ? degInt[i] : 0;
    sc[tid] = c;
    __syncthreads();
    for (int off = 1; off < SCAN_B; off <<= 1) {
        int v = (tid >= off) ? sc[tid - off] : 0;
        __syncthreads();
        sc[tid] += v;
        __syncthreads();
    }
    if (i < n) {
        int excl = sc[tid] - c;
        row_ptr[i] = blockoff[blockIdx.x] + excl;
        dinv[i] = rsqrtf((float)(c + 1));
    }
    if (blockIdx.x == 0 && tid == 0) row_ptr[n] = blockoff[nb];
}

__global__ void fill_kernel(const int* __restrict__ src, const int* __restrict__ dst,
                            const int* __restrict__ row_ptr, int* cursor,
                            const float* __restrict__ dinv,
                            int* __restrict__ col, float* __restrict__ coefv, int e) {
    int i = blockIdx.x * blockDim.x + threadIdx.x;
    if (i < e) {
        int d = dst[i];
        int s = src[i];
        int pos = row_ptr[d] + atomicAdd(&cursor[d], 1);
        col[pos] = s;
        coefv[pos] = dinv[s] * dinv[d];
    }
}

// ---------------- GEMM: Hh[n x 128] (fp16) = X[n x 128] (fp32) @ W[128 x 128] ----------------

__global__ __launch_bounds__(256) void gemm_kernel(const float* __restrict__ X,
                                                   const float* __restrict__ W,
                                                   __half* __restrict__ Hh, int n) {
    __shared__ float xs[64 * 128];  // 32 KB
    const int row0 = blockIdx.x * 64;
    const int tid = threadIdx.x;

    const float4* X4 = (const float4*)X;
    float4* xs4 = (float4*)xs;
#pragma unroll
    for (int q = 0; q < 8; ++q) {
        int idx = tid + q * 256;
        int r = idx >> 5;
        int c4 = idx & 31;
        int gr = row0 + r; if (gr >= n) gr = n - 1;
        xs4[idx] = X4[gr * D4 + c4];
    }
    __syncthreads();

    const int tx = tid & 31;
    const int ty = tid >> 5;
    float4 acc[8];
#pragma unroll
    for (int i = 0; i < 8; ++i) acc[i] = make_float4(0.f, 0.f, 0.f, 0.f);

    const float4* W4 = (const float4*)W;
    for (int k4 = 0; k4 < 32; ++k4) {
        float4 a[8];
#pragma unroll
        for (int i = 0; i < 8; ++i) a[i] = xs4[(ty * 8 + i) * 32 + k4];
#pragma unroll
        for (int kk = 0; kk < 4; ++kk) {
            float4 w = W4[(k4 * 4 + kk) * 32 + tx];
#pragma unroll
            for (int i = 0; i < 8; ++i) {
                float av = (kk == 0) ? a[i].x : (kk == 1) ? a[i].y : (kk == 2) ? a[i].z : a[i].w;
                acc[i].x = fmaf(av, w.x, acc[i].x);
                acc[i].y = fmaf(av, w.y, acc[i].y);
                acc[i].z = fmaf(av, w.z, acc[i].z);
                acc[i].w = fmaf(av, w.w, acc[i].w);
            }
        }
    }

    uint2* H8 = (uint2*)Hh;  // 4 halves per uint2; row = 32 uint2
#pragma unroll
    for (int i = 0; i < 8; ++i) {
        int r = row0 + ty * 8 + i;
        if (r < n) {
            __half2 lo = __floats2half2_rn(acc[i].x, acc[i].y);
            __half2 hi = __floats2half2_rn(acc[i].z, acc[i].w);
            uint2 pk;
            pk.x = *(unsigned int*)&lo;
            pk.y = *(unsigned int*)&hi;
            H8[(size_t)r * 32 + tx] = pk;
        }
    }
}

// ---------------- Aggregation ----------------
// Y[v] = relu( sum_{e->v} coef*Hh[src] + dinv[v]^2 * Hh[v] + b )
// One wave per node; lane owns a half2 (features 2l, 2l+1). Batch-8 gathers
// (R3 structure: VGPR ~28, occupancy ~68% — measured best).

#define AB 8

__global__ __launch_bounds__(256) void agg_kernel(const __half* __restrict__ H,
                                                  const int* __restrict__ col,
                                                  const float* __restrict__ coefv,
                                                  const int* __restrict__ row_ptr,
                                                  const float* __restrict__ dinv,
                                                  const float* __restrict__ bias,
                                                  float* __restrict__ Y, int n) {
    int wave = threadIdx.x >> 6;
    int lane = threadIdx.x & 63;
    int v = blockIdx.x * 4 + wave;
    if (v >= n) return;

    const unsigned int* H2 = (const unsigned int*)H;  // one half2 per lane
    union cvt_t { unsigned int u; __half2 h; };

    float di = dinv[v];
    float selfc = di * di;
    cvt_t cv; cv.u = H2[(size_t)v * DH2 + lane];
    float2 hv = __half22float2(cv.h);
    float ax = hv.x * selfc;
    float ay = hv.y * selfc;

    int e0 = row_ptr[v];
    int e1 = row_ptr[v + 1];
    int e = e0;
    for (; e + AB <= e1; e += AB) {
        int s[AB]; float c[AB]; unsigned int hu[AB];
#pragma unroll
        for (int j = 0; j < AB; ++j) { s[j] = col[e + j]; c[j] = coefv[e + j]; }
#pragma unroll
        for (int j = 0; j < AB; ++j) hu[j] = H2[(size_t)s[j] * DH2 + lane];
#pragma unroll
        for (int j = 0; j < AB; ++j) {
            cvt_t t; t.u = hu[j];
            float2 hs = __half22float2(t.h);
            ax = fmaf(hs.x, c[j], ax);
            ay = fmaf(hs.y, c[j], ay);
        }
    }
    for (; e < e1; ++e) {
        int s = col[e];
        float c = coefv[e];
        cvt_t t; t.u = H2[(size_t)s * DH2 + lane];
        float2 hs = __half22float2(t.h);
        ax = fmaf(hs.x, c, ax);
        ay = fmaf(hs.y, c, ay);
    }
    float2 bv = ((const float2*)bias)[lane];
    float ox = ax + bv.x;
    float oy = ay + bv.y;
    ox = ox > 0.f ? ox : 0.f;
    oy = oy > 0.f ? oy : 0.f;
    ((float2*)Y)[(size_t)v * 64 + lane] = make_float2(ox, oy);
}

// ---------------- launch ----------------

extern "C" void kernel_launch(void* const* d_in, const int* in_sizes, int n_in,
                              void* d_out, int out_size, void* d_ws, size_t ws_size,
                              hipStream_t stream) {
    const float* x = (const float*)d_in[0];
    const int* ei = (const int*)d_in[1];
    const float* W = (const float*)d_in[2];
    const float* b = (const float*)d_in[3];
    float* out = (float*)d_out;

    const int N = in_sizes[0] / D;       // 50000
    const int E = in_sizes[1] / 2;       // 800000

    const int* src = ei;
    const int* dst = ei + E;

    int* wsi = (int*)d_ws;
    float* wsf = (float*)d_ws;
    const size_t o_deg    = 0;               // N ints (zeroed)
    const size_t o_cursor = o_deg + 50000;   // N ints (zeroed)
    const size_t o_dinv   = o_cursor + 50000;// N floats
    const size_t o_rp     = o_dinv + 50000;  // N+1 ints (pad to 50016)
    const size_t o_part   = o_rp + 50016;    // 256 ints
    const size_t o_boff   = o_part + 256;    // 256 ints
    const size_t o_col    = o_boff + 256;    // E ints
    const size_t o_coef   = o_col + 800000;  // E floats
    const size_t o_h      = o_coef + 800000; // N*D halves = N*64 words (3.2M words)
    const size_t o_y1     = o_h + 3200000;   // N*D floats

    int* degInt  = wsi + o_deg;
    int* cursor  = wsi + o_cursor;
    float* dinv  = wsf + o_dinv;
    int* row_ptr = wsi + o_rp;
    int* partial = wsi + o_part;
    int* blockoff= wsi + o_boff;
    int* col     = wsi + o_col;
    float* coefv = wsf + o_coef;
    __half* h    = (__half*)(wsi + o_h);
    float* y1    = wsf + o_y1;

    const int nb_e = (E + 255) / 256;           // 3125
    const int nb_s = (N + SCAN_B - 1) / SCAN_B; // 196

    hipMemsetAsync(degInt, 0, (size_t)2 * 50000 * sizeof(int), stream);  // deg + cursor
    count_kernel<<<nb_e, 256, 0, stream>>>(dst, degInt, E);
    scanA_kernel<<<nb_s, SCAN_B, 0, stream>>>(degInt, partial, N);
    scanB_kernel<<<1, 256, 0, stream>>>(partial, blockoff, nb_s);
    scanC_kernel<<<nb_s, SCAN_B, 0, stream>>>(degInt, blockoff, row_ptr, dinv, N, nb_s);
    fill_kernel<<<nb_e, 256, 0, stream>>>(src, dst, row_ptr, cursor, dinv, col, coefv, E);

    const int nb_gemm = (N + 63) / 64;   // 782
    const int nb_agg  = (N + 3) / 4;     // 12500

    gemm_kernel<<<nb_gemm, 256, 0, stream>>>(x, W, h, N);
    agg_kernel<<<nb_agg, 256, 0, stream>>>(h, col, coefv, row_ptr, dinv, b, y1, N);
    gemm_kernel<<<nb_gemm, 256, 0, stream>>>(y1, W + D * D, h, N);
    agg_kernel<<<nb_agg, 256, 0, stream>>>(h, col, coefv, row_ptr, dinv, b + D, out, N);
}

// Round 6
// 305.929 us; speedup vs baseline: 1.2154x; 1.0229x over previous
//
#include <hip/hip_runtime.h>
#include <hip/hip_fp16.h>

// StaticGNN: 2-layer GCN. N=50000, E=800000, D=128, fp32 in/out.
// out = relu( D^{-1/2}(A+I)D^{-1/2} (X W_l) + b_l ), stacked twice.
// H stored fp16 (halves random-gather bytes). CSR edge records packed as
// int2 {src, coef} so the counting-sort scatter dirties ONE line per edge.

#define D 128
#define D4 32    // D/4 float4s per fp32 row
#define DH2 64   // D/2 half2 (uint) per fp16 row
#define SCAN_B 256

// ---------------- setup kernels ----------------

__global__ void count_kernel(const int* __restrict__ dst, int* degInt, int e) {
    int i = blockIdx.x * blockDim.x + threadIdx.x;
    if (i < e) atomicAdd(&degInt[dst[i]], 1);
}

__global__ __launch_bounds__(SCAN_B) void scanA_kernel(const int* __restrict__ degInt,
                                                       int* __restrict__ partial, int n) {
    __shared__ int red[SCAN_B / 64];
    int tid = threadIdx.x;
    int i = blockIdx.x * SCAN_B + tid;
    int c = (i < n) ? degInt[i] : 0;
    int s = c;
    for (int off = 32; off > 0; off >>= 1) s += __shfl_down(s, off, 64);
    if ((tid & 63) == 0) red[tid >> 6] = s;
    __syncthreads();
    if (tid == 0) {
        int t = 0;
#pragma unroll
        for (int w = 0; w < SCAN_B / 64; ++w) t += red[w];
        partial[blockIdx.x] = t;
    }
}

__global__ __launch_bounds__(256) void scanB_kernel(const int* __restrict__ partial,
                                                    int* __restrict__ blockoff, int nb) {
    __shared__ int sc[256];
    int tid = threadIdx.x;
    int c = (tid < nb) ? partial[tid] : 0;
    sc[tid] = c;
    __syncthreads();
    for (int off = 1; off < 256; off <<= 1) {
        int v = (tid >= off) ? sc[tid - off] : 0;
        __syncthreads();
        sc[tid] += v;
        __syncthreads();
    }
    if (tid <= nb) blockoff[tid] = (tid == 0) ? 0 : sc[tid - 1];
}

// Phase C: row_ptr + dinv + cursor (cursor starts at row_ptr for the fill scatter).
__global__ __launch_bounds__(SCAN_B) void scanC_kernel(const int* __restrict__ degInt,
                                                       const int* __restrict__ blockoff,
                                                       int* __restrict__ row_ptr,
                                                       int* __restrict__ cursor,
                                                       float* __restrict__ dinv,
                                                       int n, int nb) {
    __shared__ int sc[SCAN_B];
    int tid = threadIdx.x;
    int i = blockIdx.x * SCAN_B + tid;
    int c = (i < n) ? degInt[i] : 0;
    sc[tid] = c;
    __syncthreads();
    for (int off = 1; off < SCAN_B; off <<= 1) {
        int v = (tid >= off) ? sc[tid - off] : 0;
        __syncthreads();
        sc[tid] += v;
        __syncthreads();
    }
    if (i < n) {
        int base = blockoff[blockIdx.x] + sc[tid] - c;
        row_ptr[i] = base;
        cursor[i] = base;
        dinv[i] = rsqrtf((float)(c + 1));
    }
    if (blockIdx.x == 0 && tid == 0) row_ptr[n] = blockoff[nb];
}

// One 8B scattered write per edge: rec = {src, coef}.
__global__ void fill_kernel(const int* __restrict__ src, const int* __restrict__ dst,
                            int* cursor, const float* __restrict__ dinv,
                            int2* __restrict__ recs, int e) {
    int i = blockIdx.x * blockDim.x + threadIdx.x;
    if (i < e) {
        int d = dst[i];
        int s = src[i];
        int pos = atomicAdd(&cursor[d], 1);
        int2 rec;
        rec.x = s;
        float cf = dinv[s] * dinv[d];
        rec.y = __float_as_int(cf);
        recs[pos] = rec;
    }
}

// ---------------- GEMM: Hh[n x 128] (fp16) = X[n x 128] (fp32) @ W[128 x 128] ----------------

__global__ __launch_bounds__(256) void gemm_kernel(const float* __restrict__ X,
                                                   const float* __restrict__ W,
                                                   __half* __restrict__ Hh, int n) {
    __shared__ float xs[64 * 128];  // 32 KB
    const int row0 = blockIdx.x * 64;
    const int tid = threadIdx.x;

    const float4* X4 = (const float4*)X;
    float4* xs4 = (float4*)xs;
#pragma unroll
    for (int q = 0; q < 8; ++q) {
        int idx = tid + q * 256;
        int r = idx >> 5;
        int c4 = idx & 31;
        int gr = row0 + r; if (gr >= n) gr = n - 1;
        xs4[idx] = X4[gr * D4 + c4];
    }
    __syncthreads();

    const int tx = tid & 31;
    const int ty = tid >> 5;
    float4 acc[8];
#pragma unroll
    for (int i = 0; i < 8; ++i) acc[i] = make_float4(0.f, 0.f, 0.f, 0.f);

    const float4* W4 = (const float4*)W;
    for (int k4 = 0; k4 < 32; ++k4) {
        float4 a[8];
#pragma unroll
        for (int i = 0; i < 8; ++i) a[i] = xs4[(ty * 8 + i) * 32 + k4];
#pragma unroll
        for (int kk = 0; kk < 4; ++kk) {
            float4 w = W4[(k4 * 4 + kk) * 32 + tx];
#pragma unroll
            for (int i = 0; i < 8; ++i) {
                float av = (kk == 0) ? a[i].x : (kk == 1) ? a[i].y : (kk == 2) ? a[i].z : a[i].w;
                acc[i].x = fmaf(av, w.x, acc[i].x);
                acc[i].y = fmaf(av, w.y, acc[i].y);
                acc[i].z = fmaf(av, w.z, acc[i].z);
                acc[i].w = fmaf(av, w.w, acc[i].w);
            }
        }
    }

    uint2* H8 = (uint2*)Hh;  // 4 halves per uint2; row = 32 uint2
#pragma unroll
    for (int i = 0; i < 8; ++i) {
        int r = row0 + ty * 8 + i;
        if (r < n) {
            __half2 lo = __floats2half2_rn(acc[i].x, acc[i].y);
            __half2 hi = __floats2half2_rn(acc[i].z, acc[i].w);
            uint2 pk;
            pk.x = *(unsigned int*)&lo;
            pk.y = *(unsigned int*)&hi;
            H8[(size_t)r * 32 + tx] = pk;
        }
    }
}

// ---------------- Aggregation ----------------
// Y[v] = relu( sum_{e->v} coef*Hh[src] + dinv[v]^2 * Hh[v] + b )
// One wave per node; lane owns a half2. Batch-8 gathers (R3-best structure).

#define AB 8

__global__ __launch_bounds__(256) void agg_kernel(const __half* __restrict__ H,
                                                  const int2* __restrict__ recs,
                                                  const int* __restrict__ row_ptr,
                                                  const float* __restrict__ dinv,
                                                  const float* __restrict__ bias,
                                                  float* __restrict__ Y, int n) {
    int wave = threadIdx.x >> 6;
    int lane = threadIdx.x & 63;
    int v = blockIdx.x * 4 + wave;
    if (v >= n) return;

    const unsigned int* H2 = (const unsigned int*)H;  // one half2 per lane
    union cvt_t { unsigned int u; __half2 h; };

    float di = dinv[v];
    float selfc = di * di;
    cvt_t cv; cv.u = H2[(size_t)v * DH2 + lane];
    float2 hv = __half22float2(cv.h);
    float ax = hv.x * selfc;
    float ay = hv.y * selfc;

    int e0 = row_ptr[v];
    int e1 = row_ptr[v + 1];
    int e = e0;
    for (; e + AB <= e1; e += AB) {
        int2 r[AB]; unsigned int hu[AB];
#pragma unroll
        for (int j = 0; j < AB; ++j) r[j] = recs[e + j];
#pragma unroll
        for (int j = 0; j < AB; ++j) hu[j] = H2[(size_t)r[j].x * DH2 + lane];
#pragma unroll
        for (int j = 0; j < AB; ++j) {
            cvt_t t; t.u = hu[j];
            float2 hs = __half22float2(t.h);
            float c = __int_as_float(r[j].y);
            ax = fmaf(hs.x, c, ax);
            ay = fmaf(hs.y, c, ay);
        }
    }
    for (; e < e1; ++e) {
        int2 r = recs[e];
        cvt_t t; t.u = H2[(size_t)r.x * DH2 + lane];
        float2 hs = __half22float2(t.h);
        float c = __int_as_float(r.y);
        ax = fmaf(hs.x, c, ax);
        ay = fmaf(hs.y, c, ay);
    }
    float2 bv = ((const float2*)bias)[lane];
    float ox = ax + bv.x;
    float oy = ay + bv.y;
    ox = ox > 0.f ? ox : 0.f;
    oy = oy > 0.f ? oy : 0.f;
    ((float2*)Y)[(size_t)v * 64 + lane] = make_float2(ox, oy);
}

// ---------------- launch ----------------

extern "C" void kernel_launch(void* const* d_in, const int* in_sizes, int n_in,
                              void* d_out, int out_size, void* d_ws, size_t ws_size,
                              hipStream_t stream) {
    const float* x = (const float*)d_in[0];
    const int* ei = (const int*)d_in[1];
    const float* W = (const float*)d_in[2];
    const float* b = (const float*)d_in[3];
    float* out = (float*)d_out;

    const int N = in_sizes[0] / D;       // 50000
    const int E = in_sizes[1] / 2;       // 800000

    const int* src = ei;
    const int* dst = ei + E;

    int* wsi = (int*)d_ws;
    float* wsf = (float*)d_ws;
    const size_t o_deg    = 0;               // N ints (zeroed by memset)
    const size_t o_cursor = o_deg + 50000;   // N ints (init by scanC)
    const size_t o_dinv   = o_cursor + 50000;// N floats
    const size_t o_rp     = o_dinv + 50000;  // N+1 ints (pad to 50016)
    const size_t o_part   = o_rp + 50016;    // 256 ints
    const size_t o_boff   = o_part + 256;    // 256 ints -> ends 200528 (8B-aligned)
    const size_t o_rec    = o_boff + 256;    // E int2 = 2E words
    const size_t o_h      = o_rec + 1600000; // N*D halves = N*64 words
    const size_t o_y1     = o_h + 3200000;   // N*D floats

    int* degInt  = wsi + o_deg;
    int* cursor  = wsi + o_cursor;
    float* dinv  = wsf + o_dinv;
    int* row_ptr = wsi + o_rp;
    int* partial = wsi + o_part;
    int* blockoff= wsi + o_boff;
    int2* recs   = (int2*)(wsi + o_rec);
    __half* h    = (__half*)(wsi + o_h);
    float* y1    = wsf + o_y1;

    const int nb_e = (E + 255) / 256;           // 3125
    const int nb_s = (N + SCAN_B - 1) / SCAN_B; // 196

    hipMemsetAsync(degInt, 0, (size_t)50000 * sizeof(int), stream);
    count_kernel<<<nb_e, 256, 0, stream>>>(dst, degInt, E);
    scanA_kernel<<<nb_s, SCAN_B, 0, stream>>>(degInt, partial, N);
    scanB_kernel<<<1, 256, 0, stream>>>(partial, blockoff, nb_s);
    scanC_kernel<<<nb_s, SCAN_B, 0, stream>>>(degInt, blockoff, row_ptr, cursor, dinv, N, nb_s);
    fill_kernel<<<nb_e, 256, 0, stream>>>(src, dst, cursor, dinv, recs, E);

    const int nb_gemm = (N + 63) / 64;   // 782
    const int nb_agg  = (N + 3) / 4;     // 12500

    gemm_kernel<<<nb_gemm, 256, 0, stream>>>(x, W, h, N);
    agg_kernel<<<nb_agg, 256, 0, stream>>>(h, recs, row_ptr, dinv, b, y1, N);
    gemm_kernel<<<nb_gemm, 256, 0, stream>>>(y1, W + D * D, h, N);
    agg_kernel<<<nb_agg, 256, 0, stream>>>(h, recs, row_ptr, dinv, b + D, out, N);
}

// Round 7
// 279.228 us; speedup vs baseline: 1.3317x; 1.0956x over previous
//
#include <hip/hip_runtime.h>
#include <hip/hip_fp16.h>

// StaticGNN: 2-layer GCN. N=50000, E=800000, D=128, fp32 in/out.
// out = relu( D^{-1/2}(A+I)D^{-1/2} (X W_l) + b_l ), stacked twice.
// H stored fp16 (halves random-gather bytes). CSR records int2 {src, coef}.
// Counting sort: count_kernel's atomicAdd RETURN is the within-segment rank,
// so the fill scatter needs no atomics at all (R6 fill was atomic-bound).

#define D 128
#define D4 32    // D/4 float4s per fp32 row
#define DH2 64   // D/2 half2 (uint) per fp16 row
#define SCAN_B 256

// ---------------- setup kernels ----------------

// degInt zeroed by memset. rank[i] = # earlier edges with same dst.
__global__ void count_kernel(const int* __restrict__ dst, int* degInt,
                             int* __restrict__ rank, int e) {
    int i = blockIdx.x * blockDim.x + threadIdx.x;
    if (i < e) rank[i] = atomicAdd(&degInt[dst[i]], 1);
}

__global__ __launch_bounds__(SCAN_B) void scanA_kernel(const int* __restrict__ degInt,
                                                       int* __restrict__ partial, int n) {
    __shared__ int red[SCAN_B / 64];
    int tid = threadIdx.x;
    int i = blockIdx.x * SCAN_B + tid;
    int c = (i < n) ? degInt[i] : 0;
    int s = c;
    for (int off = 32; off > 0; off >>= 1) s += __shfl_down(s, off, 64);
    if ((tid & 63) == 0) red[tid >> 6] = s;
    __syncthreads();
    if (tid == 0) {
        int t = 0;
#pragma unroll
        for (int w = 0; w < SCAN_B / 64; ++w) t += red[w];
        partial[blockIdx.x] = t;
    }
}

__global__ __launch_bounds__(256) void scanB_kernel(const int* __restrict__ partial,
                                                    int* __restrict__ blockoff, int nb) {
    __shared__ int sc[256];
    int tid = threadIdx.x;
    int c = (tid < nb) ? partial[tid] : 0;
    sc[tid] = c;
    __syncthreads();
    for (int off = 1; off < 256; off <<= 1) {
        int v = (tid >= off) ? sc[tid - off] : 0;
        __syncthreads();
        sc[tid] += v;
        __syncthreads();
    }
    if (tid <= nb) blockoff[tid] = (tid == 0) ? 0 : sc[tid - 1];
}

__global__ __launch_bounds__(SCAN_B) void scanC_kernel(const int* __restrict__ degInt,
                                                       const int* __restrict__ blockoff,
                                                       int* __restrict__ row_ptr,
                                                       float* __restrict__ dinv,
                                                       int n, int nb) {
    __shared__ int sc[SCAN_B];
    int tid = threadIdx.x;
    int i = blockIdx.x * SCAN_B + tid;
    int c = (i < n) ? degInt[i] : 0;
    sc[tid] = c;
    __syncthreads();
    for (int off = 1; off < SCAN_B; off <<= 1) {
        int v = (tid >= off) ? sc[tid - off] : 0;
        __syncthreads();
        sc[tid] += v;
        __syncthreads();
    }
    if (i < n) {
        int base = blockoff[blockIdx.x] + sc[tid] - c;
        row_ptr[i] = base;
        dinv[i] = rsqrtf((float)(c + 1));
    }
    if (blockIdx.x == 0 && tid == 0) row_ptr[n] = blockoff[nb];
}

// Atomic-free scatter: pos = row_ptr[d] + rank[i]; one 8B random store per edge.
// row_ptr/dinv are 200KB total -> L2-hot; loads independent; store fire-and-forget.
__global__ void fill_kernel(const int* __restrict__ src, const int* __restrict__ dst,
                            const int* __restrict__ rank,
                            const int* __restrict__ row_ptr,
                            const float* __restrict__ dinv,
                            int2* __restrict__ recs, int e) {
    int i = blockIdx.x * blockDim.x + threadIdx.x;
    if (i < e) {
        int d = dst[i];
        int s = src[i];
        int pos = row_ptr[d] + rank[i];
        int2 rec;
        rec.x = s;
        rec.y = __float_as_int(dinv[s] * dinv[d]);
        recs[pos] = rec;
    }
}

// ---------------- GEMM: Hh[n x 128] (fp16) = X[n x 128] (fp32) @ W[128 x 128] ----------------

__global__ __launch_bounds__(256) void gemm_kernel(const float* __restrict__ X,
                                                   const float* __restrict__ W,
                                                   __half* __restrict__ Hh, int n) {
    __shared__ float xs[64 * 128];  // 32 KB
    const int row0 = blockIdx.x * 64;
    const int tid = threadIdx.x;

    const float4* X4 = (const float4*)X;
    float4* xs4 = (float4*)xs;
#pragma unroll
    for (int q = 0; q < 8; ++q) {
        int idx = tid + q * 256;
        int r = idx >> 5;
        int c4 = idx & 31;
        int gr = row0 + r; if (gr >= n) gr = n - 1;
        xs4[idx] = X4[gr * D4 + c4];
    }
    __syncthreads();

    const int tx = tid & 31;
    const int ty = tid >> 5;
    float4 acc[8];
#pragma unroll
    for (int i = 0; i < 8; ++i) acc[i] = make_float4(0.f, 0.f, 0.f, 0.f);

    const float4* W4 = (const float4*)W;
    for (int k4 = 0; k4 < 32; ++k4) {
        float4 a[8];
#pragma unroll
        for (int i = 0; i < 8; ++i) a[i] = xs4[(ty * 8 + i) * 32 + k4];
#pragma unroll
        for (int kk = 0; kk < 4; ++kk) {
            float4 w = W4[(k4 * 4 + kk) * 32 + tx];
#pragma unroll
            for (int i = 0; i < 8; ++i) {
                float av = (kk == 0) ? a[i].x : (kk == 1) ? a[i].y : (kk == 2) ? a[i].z : a[i].w;
                acc[i].x = fmaf(av, w.x, acc[i].x);
                acc[i].y = fmaf(av, w.y, acc[i].y);
                acc[i].z = fmaf(av, w.z, acc[i].z);
                acc[i].w = fmaf(av, w.w, acc[i].w);
            }
        }
    }

    uint2* H8 = (uint2*)Hh;  // 4 halves per uint2; row = 32 uint2
#pragma unroll
    for (int i = 0; i < 8; ++i) {
        int r = row0 + ty * 8 + i;
        if (r < n) {
            __half2 lo = __floats2half2_rn(acc[i].x, acc[i].y);
            __half2 hi = __floats2half2_rn(acc[i].z, acc[i].w);
            uint2 pk;
            pk.x = *(unsigned int*)&lo;
            pk.y = *(unsigned int*)&hi;
            H8[(size_t)r * 32 + tx] = pk;
        }
    }
}

// ---------------- Aggregation ----------------
// Y[v] = relu( sum_{e->v} coef*Hh[src] + dinv[v]^2 * Hh[v] + b )
// One wave per node; lane owns a half2. Batch-8 gathers (measured best).

#define AB 8

__global__ __launch_bounds__(256) void agg_kernel(const __half* __restrict__ H,
                                                  const int2* __restrict__ recs,
                                                  const int* __restrict__ row_ptr,
                                                  const float* __restrict__ dinv,
                                                  const float* __restrict__ bias,
                                                  float* __restrict__ Y, int n) {
    int wave = threadIdx.x >> 6;
    int lane = threadIdx.x & 63;
    int v = blockIdx.x * 4 + wave;
    if (v >= n) return;

    const unsigned int* H2 = (const unsigned int*)H;  // one half2 per lane
    union cvt_t { unsigned int u; __half2 h; };

    float di = dinv[v];
    float selfc = di * di;
    cvt_t cv; cv.u = H2[(size_t)v * DH2 + lane];
    float2 hv = __half22float2(cv.h);
    float ax = hv.x * selfc;
    float ay = hv.y * selfc;

    int e0 = row_ptr[v];
    int e1 = row_ptr[v + 1];
    int e = e0;
    for (; e + AB <= e1; e += AB) {
        int2 r[AB]; unsigned int hu[AB];
#pragma unroll
        for (int j = 0; j < AB; ++j) r[j] = recs[e + j];
#pragma unroll
        for (int j = 0; j < AB; ++j) hu[j] = H2[(size_t)r[j].x * DH2 + lane];
#pragma unroll
        for (int j = 0; j < AB; ++j) {
            cvt_t t; t.u = hu[j];
            float2 hs = __half22float2(t.h);
            float c = __int_as_float(r[j].y);
            ax = fmaf(hs.x, c, ax);
            ay = fmaf(hs.y, c, ay);
        }
    }
    for (; e < e1; ++e) {
        int2 r = recs[e];
        cvt_t t; t.u = H2[(size_t)r.x * DH2 + lane];
        float2 hs = __half22float2(t.h);
        float c = __int_as_float(r.y);
        ax = fmaf(hs.x, c, ax);
        ay = fmaf(hs.y, c, ay);
    }
    float2 bv = ((const float2*)bias)[lane];
    float ox = ax + bv.x;
    float oy = ay + bv.y;
    ox = ox > 0.f ? ox : 0.f;
    oy = oy > 0.f ? oy : 0.f;
    ((float2*)Y)[(size_t)v * 64 + lane] = make_float2(ox, oy);
}

// ---------------- launch ----------------

extern "C" void kernel_launch(void* const* d_in, const int* in_sizes, int n_in,
                              void* d_out, int out_size, void* d_ws, size_t ws_size,
                              hipStream_t stream) {
    const float* x = (const float*)d_in[0];
    const int* ei = (const int*)d_in[1];
    const float* W = (const float*)d_in[2];
    const float* b = (const float*)d_in[3];
    float* out = (float*)d_out;

    const int N = in_sizes[0] / D;       // 50000
    const int E = in_sizes[1] / 2;       // 800000

    const int* src = ei;
    const int* dst = ei + E;

    int* wsi = (int*)d_ws;
    float* wsf = (float*)d_ws;
    const size_t o_deg    = 0;               // N ints (zeroed by memset)
    const size_t o_dinv   = o_deg + 50000;   // N floats
    const size_t o_rp     = o_dinv + 50000;  // N+1 ints (pad to 50016)
    const size_t o_part   = o_rp + 50016;    // 256 ints
    const size_t o_boff   = o_part + 256;    // 256 ints -> ends 150528 (8B-aligned)
    const size_t o_rank   = o_boff + 256;    // E ints
    const size_t o_rec    = o_rank + 800000; // E int2 = 2E words (8B-aligned)
    const size_t o_h      = o_rec + 1600000; // N*D halves = N*64 words
    const size_t o_y1     = o_h + 3200000;   // N*D floats

    int* degInt  = wsi + o_deg;
    float* dinv  = wsf + o_dinv;
    int* row_ptr = wsi + o_rp;
    int* partial = wsi + o_part;
    int* blockoff= wsi + o_boff;
    int* rank    = wsi + o_rank;
    int2* recs   = (int2*)(wsi + o_rec);
    __half* h    = (__half*)(wsi + o_h);
    float* y1    = wsf + o_y1;

    const int nb_e = (E + 255) / 256;           // 3125
    const int nb_s = (N + SCAN_B - 1) / SCAN_B; // 196

    hipMemsetAsync(degInt, 0, (size_t)50000 * sizeof(int), stream);
    count_kernel<<<nb_e, 256, 0, stream>>>(dst, degInt, rank, E);
    scanA_kernel<<<nb_s, SCAN_B, 0, stream>>>(degInt, partial, N);
    scanB_kernel<<<1, 256, 0, stream>>>(partial, blockoff, nb_s);
    scanC_kernel<<<nb_s, SCAN_B, 0, stream>>>(degInt, blockoff, row_ptr, dinv, N, nb_s);
    fill_kernel<<<nb_e, 256, 0, stream>>>(src, dst, rank, row_ptr, dinv, recs, E);

    const int nb_gemm = (N + 63) / 64;   // 782
    const int nb_agg  = (N + 3) / 4;     // 12500

    gemm_kernel<<<nb_gemm, 256, 0, stream>>>(x, W, h, N);
    agg_kernel<<<nb_agg, 256, 0, stream>>>(h, recs, row_ptr, dinv, b, y1, N);
    gemm_kernel<<<nb_gemm, 256, 0, stream>>>(y1, W + D * D, h, N);
    agg_kernel<<<nb_agg, 256, 0, stream>>>(h, recs, row_ptr, dinv, b + D, out, N);
}

// Round 8
// 250.940 us; speedup vs baseline: 1.4818x; 1.1127x over previous
//
#include <hip/hip_runtime.h>
#include <hip/hip_fp16.h>

// StaticGNN: 2-layer GCN. N=50000, E=800000, D=128, fp32 in/out.
// out = relu( D^{-1/2}(A+I)D^{-1/2} (X W_l) + b_l ), stacked twice.
// H fp16 (halves gather bytes). CSR records int2 {src, coef}; counting sort
// uses count_kernel's atomic RETURN as rank (atomic-free fill).
// GEMM on matrix cores: mfma_f32_16x16x32_f16 computing H^T = W^T · X^T so
// each lane's 4 acc regs are CONTIGUOUS features -> one 8B store per tile.

#define D 128
#define DH2 64   // D/2 half2 per fp16 row
#define SCAN_B 256
#define WP 136   // LDS pitch (halves) for W^T tile: breaks 256B-stride conflicts

typedef _Float16 half8 __attribute__((ext_vector_type(8)));
typedef float floatx4 __attribute__((ext_vector_type(4)));

// ---------------- setup kernels ----------------

__global__ void count_kernel(const int* __restrict__ dst, int* degInt,
                             int* __restrict__ rank, int e) {
    int i = blockIdx.x * blockDim.x + threadIdx.x;
    if (i < e) rank[i] = atomicAdd(&degInt[dst[i]], 1);
}

__global__ __launch_bounds__(SCAN_B) void scanA_kernel(const int* __restrict__ degInt,
                                                       int* __restrict__ partial, int n) {
    __shared__ int red[SCAN_B / 64];
    int tid = threadIdx.x;
    int i = blockIdx.x * SCAN_B + tid;
    int c = (i < n) ? degInt[i] : 0;
    int s = c;
    for (int off = 32; off > 0; off >>= 1) s += __shfl_down(s, off, 64);
    if ((tid & 63) == 0) red[tid >> 6] = s;
    __syncthreads();
    if (tid == 0) {
        int t = 0;
#pragma unroll
        for (int w = 0; w < SCAN_B / 64; ++w) t += red[w];
        partial[blockIdx.x] = t;
    }
}

__global__ __launch_bounds__(256) void scanB_kernel(const int* __restrict__ partial,
                                                    int* __restrict__ blockoff, int nb) {
    __shared__ int sc[256];
    int tid = threadIdx.x;
    int c = (tid < nb) ? partial[tid] : 0;
    sc[tid] = c;
    __syncthreads();
    for (int off = 1; off < 256; off <<= 1) {
        int v = (tid >= off) ? sc[tid - off] : 0;
        __syncthreads();
        sc[tid] += v;
        __syncthreads();
    }
    if (tid <= nb) blockoff[tid] = (tid == 0) ? 0 : sc[tid - 1];
}

__global__ __launch_bounds__(SCAN_B) void scanC_kernel(const int* __restrict__ degInt,
                                                       const int* __restrict__ blockoff,
                                                       int* __restrict__ row_ptr,
                                                       float* __restrict__ dinv,
                                                       int n, int nb) {
    __shared__ int sc[SCAN_B];
    int tid = threadIdx.x;
    int i = blockIdx.x * SCAN_B + tid;
    int c = (i < n) ? degInt[i] : 0;
    sc[tid] = c;
    __syncthreads();
    for (int off = 1; off < SCAN_B; off <<= 1) {
        int v = (tid >= off) ? sc[tid - off] : 0;
        __syncthreads();
        sc[tid] += v;
        __syncthreads();
    }
    if (i < n) {
        int base = blockoff[blockIdx.x] + sc[tid] - c;
        row_ptr[i] = base;
        dinv[i] = rsqrtf((float)(c + 1));
    }
    if (blockIdx.x == 0 && tid == 0) row_ptr[n] = blockoff[nb];
}

__global__ void fill_kernel(const int* __restrict__ src, const int* __restrict__ dst,
                            const int* __restrict__ rank,
                            const int* __restrict__ row_ptr,
                            const float* __restrict__ dinv,
                            int2* __restrict__ recs, int e) {
    int i = blockIdx.x * blockDim.x + threadIdx.x;
    if (i < e) {
        int d = dst[i];
        int s = src[i];
        int pos = row_ptr[d] + rank[i];
        int2 rec;
        rec.x = s;
        rec.y = __float_as_int(dinv[s] * dinv[d]);
        recs[pos] = rec;
    }
}

// ---------------- dtype conversion ----------------

// x fp32 -> fp16, 4 elems/thread.
__global__ __launch_bounds__(256) void cvtx_kernel(const float* __restrict__ X,
                                                   __half* __restrict__ Xh, int total4) {
    int i = blockIdx.x * blockDim.x + threadIdx.x;
    if (i < total4) {
        float4 v = ((const float4*)X)[i];
        __half2 p0 = __floats2half2_rn(v.x, v.y);
        __half2 p1 = __floats2half2_rn(v.z, v.w);
        uint2 pk;
        pk.x = *(unsigned int*)&p0;
        pk.y = *(unsigned int*)&p1;
        ((uint2*)Xh)[i] = pk;
    }
}

// W[l][k][f] fp32 -> WhT[l][f][k] fp16 (transposed per layer). 2*128*128 threads.
__global__ __launch_bounds__(256) void cvtw_kernel(const float* __restrict__ W,
                                                   __half* __restrict__ WhT) {
    int id = blockIdx.x * blockDim.x + threadIdx.x;  // < 32768
    int l = id >> 14;
    int rem = id & 16383;
    int f = rem >> 7;
    int k = rem & 127;
    WhT[id] = __float2half(W[l * 16384 + k * 128 + f]);
}

// ---------------- MFMA GEMM: Hh[n][128] = Xh[n][128] @ W (via H^T = W^T X^T) ----------------
// Block: 256 thr = 4 waves; wave handles 16 nodes x 128 features.
// A = W^T (feature-major, LDS, pitch WP); B = X row (16B contiguous fp16 loads).
// C/D: col=lane&15 -> node, row=quad*4+reg -> feature (4 contiguous -> 8B store).

__global__ __launch_bounds__(256) void gemm_mfma_kernel(const __half* __restrict__ Xh,
                                                        const __half* __restrict__ WhT,
                                                        __half* __restrict__ Hh, int n) {
    __shared__ _Float16 wlds[128 * WP];
    const int tid = threadIdx.x;

    // Stage W^T [128 f][128 k] into LDS with pitch WP. 2048 x 16B chunks.
    {
        const uint2* Wg = (const uint2*)WhT;  // 8 halves per uint2? no: uint2 = 4 halves
#pragma unroll
        for (int q = 0; q < 8; ++q) {
            int idx = tid + q * 256;        // 0..2047, each = 8 halves
            int row = idx >> 4;             // f
            int col8 = (idx & 15) * 8;      // k start
            // global: WhT[row*128 + col8], 16B
            const uint2* gsrc = (const uint2*)(WhT + row * 128 + col8);
            uint2 a = gsrc[0];
            uint2 b = gsrc[1];
            uint2* ldst = (uint2*)(wlds + row * WP + col8);
            ldst[0] = a;
            ldst[1] = b;
        }
    }
    __syncthreads();

    const int wave = tid >> 6;
    const int lane = tid & 63;
    const int m = lane & 15;        // node-within-tile (B n-index, C/D col)
    const int quad = lane >> 4;

    const int node = blockIdx.x * 64 + wave * 16 + m;
    const int node_ld = node < n ? node : (n - 1);

    // B-frags: 4 k-steps of this node's fp16 row, 16B each.
    half8 bfr[4];
#pragma unroll
    for (int k = 0; k < 4; ++k) {
        bfr[k] = *(const half8*)(Xh + (size_t)node_ld * 128 + k * 32 + quad * 8);
    }

    floatx4 acc[8];
#pragma unroll
    for (int f = 0; f < 8; ++f) acc[f] = (floatx4){0.f, 0.f, 0.f, 0.f};

#pragma unroll
    for (int f = 0; f < 8; ++f) {
#pragma unroll
        for (int k = 0; k < 4; ++k) {
            half8 a = *(const half8*)(wlds + (f * 16 + m) * WP + k * 32 + quad * 8);
            acc[f] = __builtin_amdgcn_mfma_f32_16x16x32_f16(a, bfr[k], acc[f], 0, 0, 0);
        }
    }

    if (node < n) {
#pragma unroll
        for (int f = 0; f < 8; ++f) {
            __half2 p0 = __floats2half2_rn(acc[f][0], acc[f][1]);
            __half2 p1 = __floats2half2_rn(acc[f][2], acc[f][3]);
            uint2 pk;
            pk.x = *(unsigned int*)&p0;
            pk.y = *(unsigned int*)&p1;
            // features f*16 + quad*4 .. +3 of row `node`
            *(uint2*)(Hh + (size_t)node * 128 + f * 16 + quad * 4) = pk;
        }
    }
}

// ---------------- Aggregation ----------------
// Y[v] = relu( sum coef*Hh[src] + dinv^2*Hh[v] + b ). One wave/node, batch-8.
// writeHalf: layer-0 output feeds GEMM-2, store fp16; else fp32 to d_out.

#define AB 8

__global__ __launch_bounds__(256) void agg_kernel(const __half* __restrict__ H,
                                                  const int2* __restrict__ recs,
                                                  const int* __restrict__ row_ptr,
                                                  const float* __restrict__ dinv,
                                                  const float* __restrict__ bias,
                                                  float* __restrict__ YF,
                                                  __half* __restrict__ YH,
                                                  int n, int writeHalf) {
    int wave = threadIdx.x >> 6;
    int lane = threadIdx.x & 63;
    int v = blockIdx.x * 4 + wave;
    if (v >= n) return;

    const unsigned int* H2 = (const unsigned int*)H;
    union cvt_t { unsigned int u; __half2 h; };

    float di = dinv[v];
    float selfc = di * di;
    cvt_t cv; cv.u = H2[(size_t)v * DH2 + lane];
    float2 hv = __half22float2(cv.h);
    float ax = hv.x * selfc;
    float ay = hv.y * selfc;

    int e0 = row_ptr[v];
    int e1 = row_ptr[v + 1];
    int e = e0;
    for (; e + AB <= e1; e += AB) {
        int2 r[AB]; unsigned int hu[AB];
#pragma unroll
        for (int j = 0; j < AB; ++j) r[j] = recs[e + j];
#pragma unroll
        for (int j = 0; j < AB; ++j) hu[j] = H2[(size_t)r[j].x * DH2 + lane];
#pragma unroll
        for (int j = 0; j < AB; ++j) {
            cvt_t t; t.u = hu[j];
            float2 hs = __half22float2(t.h);
            float c = __int_as_float(r[j].y);
            ax = fmaf(hs.x, c, ax);
            ay = fmaf(hs.y, c, ay);
        }
    }
    for (; e < e1; ++e) {
        int2 r = recs[e];
        cvt_t t; t.u = H2[(size_t)r.x * DH2 + lane];
        float2 hs = __half22float2(t.h);
        float c = __int_as_float(r.y);
        ax = fmaf(hs.x, c, ax);
        ay = fmaf(hs.y, c, ay);
    }
    float2 bv = ((const float2*)bias)[lane];
    float ox = ax + bv.x;
    float oy = ay + bv.y;
    ox = ox > 0.f ? ox : 0.f;
    oy = oy > 0.f ? oy : 0.f;
    if (writeHalf) {
        __half2 p = __floats2half2_rn(ox, oy);
        ((__half2*)YH)[(size_t)v * DH2 + lane] = p;
    } else {
        ((float2*)YF)[(size_t)v * DH2 + lane] = make_float2(ox, oy);
    }
}

// ---------------- launch ----------------

extern "C" void kernel_launch(void* const* d_in, const int* in_sizes, int n_in,
                              void* d_out, int out_size, void* d_ws, size_t ws_size,
                              hipStream_t stream) {
    const float* x = (const float*)d_in[0];
    const int* ei = (const int*)d_in[1];
    const float* W = (const float*)d_in[2];
    const float* b = (const float*)d_in[3];
    float* out = (float*)d_out;

    const int N = in_sizes[0] / D;       // 50000
    const int E = in_sizes[1] / 2;       // 800000

    const int* src = ei;
    const int* dst = ei + E;

    int* wsi = (int*)d_ws;
    float* wsf = (float*)d_ws;
    const size_t o_deg  = 0;                 // N ints (memset 0)
    const size_t o_dinv = o_deg + 50000;     // N floats
    const size_t o_rp   = o_dinv + 50000;    // N+1 ints (pad 50016)
    const size_t o_part = o_rp + 50016;      // 256
    const size_t o_boff = o_part + 256;      // 256 -> 150528 (even)
    const size_t o_rank = o_boff + 256;      // E ints
    const size_t o_rec  = o_rank + 800000;   // E int2
    const size_t o_h    = o_rec + 1600000;   // N*128 halves = 3.2M words
    const size_t o_xh   = o_h + 3200000;     // N*128 halves
    const size_t o_wht  = o_xh + 3200000;    // 2*128*128 halves = 16384 words
    const size_t o_y1h  = o_wht + 16384;     // N*128 halves

    int* degInt  = wsi + o_deg;
    float* dinv  = wsf + o_dinv;
    int* row_ptr = wsi + o_rp;
    int* partial = wsi + o_part;
    int* blockoff= wsi + o_boff;
    int* rank    = wsi + o_rank;
    int2* recs   = (int2*)(wsi + o_rec);
    __half* h    = (__half*)(wsi + o_h);
    __half* xh   = (__half*)(wsi + o_xh);
    __half* wht  = (__half*)(wsi + o_wht);
    __half* y1h  = (__half*)(wsi + o_y1h);

    const int nb_e = (E + 255) / 256;           // 3125
    const int nb_s = (N + SCAN_B - 1) / SCAN_B; // 196

    hipMemsetAsync(degInt, 0, (size_t)50000 * sizeof(int), stream);
    count_kernel<<<nb_e, 256, 0, stream>>>(dst, degInt, rank, E);
    scanA_kernel<<<nb_s, SCAN_B, 0, stream>>>(degInt, partial, N);
    scanB_kernel<<<1, 256, 0, stream>>>(partial, blockoff, nb_s);
    scanC_kernel<<<nb_s, SCAN_B, 0, stream>>>(degInt, blockoff, row_ptr, dinv, N, nb_s);
    fill_kernel<<<nb_e, 256, 0, stream>>>(src, dst, rank, row_ptr, dinv, recs, E);

    cvtx_kernel<<<(N * 32 + 255) / 256, 256, 0, stream>>>(x, xh, N * 32);  // N*128/4
    cvtw_kernel<<<128, 256, 0, stream>>>(W, wht);

    const int nb_gemm = (N + 63) / 64;   // 782
    const int nb_agg  = (N + 3) / 4;     // 12500

    gemm_mfma_kernel<<<nb_gemm, 256, 0, stream>>>(xh, wht, h, N);
    agg_kernel<<<nb_agg, 256, 0, stream>>>(h, recs, row_ptr, dinv, b, nullptr, y1h, N, 1);
    gemm_mfma_kernel<<<nb_gemm, 256, 0, stream>>>(y1h, wht + 16384, h, N);
    agg_kernel<<<nb_agg, 256, 0, stream>>>(h, recs, row_ptr, dinv, b + D, out, nullptr, N, 0);
}

// Round 9
// 243.165 us; speedup vs baseline: 1.5291x; 1.0320x over previous
//
#include <hip/hip_runtime.h>
#include <hip/hip_fp16.h>

// StaticGNN: 2-layer GCN. N=50000, E=800000, D=128, fp32 in/out.
// out = relu( D^{-1/2}(A+I)D^{-1/2} (X W_l) + b_l ), x2.
// H fp16; CSR recs int2{src,coef}; counting-sort rank from count's atomic return.
// GEMM: mfma_f32_16x16x32_f16, H^T = W^T X^T (contiguous-feature stores);
//       layer-1 converts x fp32->fp16 in-kernel (no cvtx pass).
// AGG: half-wave per edge (2 edge rows per vmem inst), batch 8 insts = 16 edges.

#define D 128
#define SCAN_B 256
#define WP 136   // LDS pitch (halves) for W^T tile
#define ABI 8    // vmem insts per agg batch; 2 edges per inst

typedef _Float16 half8 __attribute__((ext_vector_type(8)));
typedef float floatx4 __attribute__((ext_vector_type(4)));

// ---------------- setup kernels ----------------

__global__ void count_kernel(const int* __restrict__ dst, int* degInt,
                             int* __restrict__ rank, int e) {
    int i = blockIdx.x * blockDim.x + threadIdx.x;
    if (i < e) rank[i] = atomicAdd(&degInt[dst[i]], 1);
}

__global__ __launch_bounds__(SCAN_B) void scanA_kernel(const int* __restrict__ degInt,
                                                       int* __restrict__ partial, int n) {
    __shared__ int red[SCAN_B / 64];
    int tid = threadIdx.x;
    int i = blockIdx.x * SCAN_B + tid;
    int c = (i < n) ? degInt[i] : 0;
    int s = c;
    for (int off = 32; off > 0; off >>= 1) s += __shfl_down(s, off, 64);
    if ((tid & 63) == 0) red[tid >> 6] = s;
    __syncthreads();
    if (tid == 0) {
        int t = 0;
#pragma unroll
        for (int w = 0; w < SCAN_B / 64; ++w) t += red[w];
        partial[blockIdx.x] = t;
    }
}

__global__ __launch_bounds__(256) void scanB_kernel(const int* __restrict__ partial,
                                                    int* __restrict__ blockoff, int nb) {
    __shared__ int sc[256];
    int tid = threadIdx.x;
    int c = (tid < nb) ? partial[tid] : 0;
    sc[tid] = c;
    __syncthreads();
    for (int off = 1; off < 256; off <<= 1) {
        int v = (tid >= off) ? sc[tid - off] : 0;
        __syncthreads();
        sc[tid] += v;
        __syncthreads();
    }
    if (tid <= nb) blockoff[tid] = (tid == 0) ? 0 : sc[tid - 1];
}

__global__ __launch_bounds__(SCAN_B) void scanC_kernel(const int* __restrict__ degInt,
                                                       const int* __restrict__ blockoff,
                                                       int* __restrict__ row_ptr,
                                                       float* __restrict__ dinv,
                                                       int n, int nb) {
    __shared__ int sc[SCAN_B];
    int tid = threadIdx.x;
    int i = blockIdx.x * SCAN_B + tid;
    int c = (i < n) ? degInt[i] : 0;
    sc[tid] = c;
    __syncthreads();
    for (int off = 1; off < SCAN_B; off <<= 1) {
        int v = (tid >= off) ? sc[tid - off] : 0;
        __syncthreads();
        sc[tid] += v;
        __syncthreads();
    }
    if (i < n) {
        int base = blockoff[blockIdx.x] + sc[tid] - c;
        row_ptr[i] = base;
        dinv[i] = rsqrtf((float)(c + 1));
    }
    if (blockIdx.x == 0 && tid == 0) row_ptr[n] = blockoff[nb];
}

__global__ void fill_kernel(const int* __restrict__ src, const int* __restrict__ dst,
                            const int* __restrict__ rank,
                            const int* __restrict__ row_ptr,
                            const float* __restrict__ dinv,
                            int2* __restrict__ recs, int e) {
    int i = blockIdx.x * blockDim.x + threadIdx.x;
    if (i < e) {
        int d = dst[i];
        int s = src[i];
        int pos = row_ptr[d] + rank[i];
        int2 rec;
        rec.x = s;
        rec.y = __float_as_int(dinv[s] * dinv[d]);
        recs[pos] = rec;
    }
}

// W[l][k][f] fp32 -> WhT[l][f][k] fp16 (transposed per layer).
__global__ __launch_bounds__(256) void cvtw_kernel(const float* __restrict__ W,
                                                   __half* __restrict__ WhT) {
    int id = blockIdx.x * blockDim.x + threadIdx.x;  // < 32768
    int l = id >> 14;
    int rem = id & 16383;
    int f = rem >> 7;
    int k = rem & 127;
    WhT[id] = __float2half(W[l * 16384 + k * 128 + f]);
}

// ---------------- MFMA GEMM: Hh[n][128] = X[n][128] @ W (via H^T = W^T X^T) ----------------
// fromFloat: B-frags loaded fp32 and converted in-kernel (layer 1).

__global__ __launch_bounds__(256) void gemm_mfma_kernel(const float* __restrict__ Xf,
                                                        const __half* __restrict__ Xh,
                                                        const __half* __restrict__ WhT,
                                                        __half* __restrict__ Hh, int n,
                                                        int fromFloat) {
    __shared__ _Float16 wlds[128 * WP];
    const int tid = threadIdx.x;

    // Stage W^T [128 f][128 k] into LDS (pitch WP), 16B chunks.
#pragma unroll
    for (int q = 0; q < 8; ++q) {
        int idx = tid + q * 256;        // 0..2047, each = 8 halves
        int row = idx >> 4;
        int col8 = (idx & 15) * 8;
        const uint2* gsrc = (const uint2*)(WhT + row * 128 + col8);
        uint2 a = gsrc[0];
        uint2 b = gsrc[1];
        uint2* ldst = (uint2*)(wlds + row * WP + col8);
        ldst[0] = a;
        ldst[1] = b;
    }
    __syncthreads();

    const int wave = tid >> 6;
    const int lane = tid & 63;
    const int m = lane & 15;
    const int quad = lane >> 4;

    const int node = blockIdx.x * 64 + wave * 16 + m;
    const int node_ld = node < n ? node : (n - 1);

    half8 bfr[4];
    if (fromFloat) {
#pragma unroll
        for (int k = 0; k < 4; ++k) {
            const float4* p = (const float4*)(Xf + (size_t)node_ld * 128 + k * 32 + quad * 8);
            float4 lo = p[0];
            float4 hi = p[1];
            half8 h;
            h[0] = (_Float16)lo.x; h[1] = (_Float16)lo.y;
            h[2] = (_Float16)lo.z; h[3] = (_Float16)lo.w;
            h[4] = (_Float16)hi.x; h[5] = (_Float16)hi.y;
            h[6] = (_Float16)hi.z; h[7] = (_Float16)hi.w;
            bfr[k] = h;
        }
    } else {
#pragma unroll
        for (int k = 0; k < 4; ++k) {
            bfr[k] = *(const half8*)(Xh + (size_t)node_ld * 128 + k * 32 + quad * 8);
        }
    }

    floatx4 acc[8];
#pragma unroll
    for (int f = 0; f < 8; ++f) acc[f] = (floatx4){0.f, 0.f, 0.f, 0.f};

#pragma unroll
    for (int f = 0; f < 8; ++f) {
#pragma unroll
        for (int k = 0; k < 4; ++k) {
            half8 a = *(const half8*)(wlds + (f * 16 + m) * WP + k * 32 + quad * 8);
            acc[f] = __builtin_amdgcn_mfma_f32_16x16x32_f16(a, bfr[k], acc[f], 0, 0, 0);
        }
    }

    if (node < n) {
#pragma unroll
        for (int f = 0; f < 8; ++f) {
            __half2 p0 = __floats2half2_rn(acc[f][0], acc[f][1]);
            __half2 p1 = __floats2half2_rn(acc[f][2], acc[f][3]);
            uint2 pk;
            pk.x = *(unsigned int*)&p0;
            pk.y = *(unsigned int*)&p1;
            *(uint2*)(Hh + (size_t)node * 128 + f * 16 + quad * 4) = pk;
        }
    }
}

// ---------------- Aggregation ----------------
// Y[v] = relu( sum coef*Hh[src] + dinv^2*Hh[v] + b ). One wave/node.
// Half-wave per edge: lane = (sub, fl); sub in {0,1} picks edge of pair,
// fl in [0,32) picks 4-feature slice (uint2 = 4 halves). One vmem inst
// fetches TWO edge rows. Batch ABI=8 insts = 16 edges; guarded tail batch.

__device__ inline float4 unpack4(uint2 u) {
    union { unsigned int x; __half2 h; } a, b;
    a.x = u.x; b.x = u.y;
    float2 f0 = __half22float2(a.h);
    float2 f1 = __half22float2(b.h);
    return make_float4(f0.x, f0.y, f1.x, f1.y);
}

__global__ __launch_bounds__(256) void agg_kernel(const __half* __restrict__ H,
                                                  const int2* __restrict__ recs,
                                                  const int* __restrict__ row_ptr,
                                                  const float* __restrict__ dinv,
                                                  const float* __restrict__ bias,
                                                  float* __restrict__ YF,
                                                  __half* __restrict__ YH,
                                                  int n, int writeHalf) {
    int wave = threadIdx.x >> 6;
    int lane = threadIdx.x & 63;
    int v = blockIdx.x * 4 + wave;
    if (v >= n) return;

    const int sub = lane >> 5;   // which edge of the pair
    const int fl  = lane & 31;   // 4-feature slice
    const uint2* H4 = (const uint2*)H;  // row = 32 uint2

    float di = dinv[v];
    float selfc = (sub == 0) ? di * di : 0.f;
    float4 hself = unpack4(H4[(size_t)v * 32 + fl]);
    float ax = hself.x * selfc;
    float ay = hself.y * selfc;
    float az = hself.z * selfc;
    float aw = hself.w * selfc;

    int e0 = row_ptr[v];
    int e1 = row_ptr[v + 1];
    int e = e0;
    // main batches: 16 edges per iteration, 8 vmem gathers in flight
    for (; e + 2 * ABI <= e1; e += 2 * ABI) {
        int2 r[ABI]; uint2 hu[ABI];
#pragma unroll
        for (int j = 0; j < ABI; ++j) r[j] = recs[e + 2 * j + sub];
#pragma unroll
        for (int j = 0; j < ABI; ++j) hu[j] = H4[(size_t)r[j].x * 32 + fl];
#pragma unroll
        for (int j = 0; j < ABI; ++j) {
            float c = __int_as_float(r[j].y);
            float4 hs = unpack4(hu[j]);
            ax = fmaf(hs.x, c, ax);
            ay = fmaf(hs.y, c, ay);
            az = fmaf(hs.z, c, az);
            aw = fmaf(hs.w, c, aw);
        }
    }
    // guarded tail batch (covers up to 15 remaining edges; loads grouped
    // before uses so gathers still overlap)
    if (e < e1) {
        int2 r[ABI]; uint2 hu[ABI]; bool act[ABI];
#pragma unroll
        for (int j = 0; j < ABI; ++j) {
            int idx = e + 2 * j + sub;
            act[j] = idx < e1;
            if (act[j]) r[j] = recs[idx];
        }
#pragma unroll
        for (int j = 0; j < ABI; ++j) {
            if (act[j]) hu[j] = H4[(size_t)r[j].x * 32 + fl];
        }
#pragma unroll
        for (int j = 0; j < ABI; ++j) {
            if (act[j]) {
                float c = __int_as_float(r[j].y);
                float4 hs = unpack4(hu[j]);
                ax = fmaf(hs.x, c, ax);
                ay = fmaf(hs.y, c, ay);
                az = fmaf(hs.z, c, az);
                aw = fmaf(hs.w, c, aw);
            }
        }
    }
    // combine the two half-wave partial sums
    ax += __shfl_xor(ax, 32);
    ay += __shfl_xor(ay, 32);
    az += __shfl_xor(az, 32);
    aw += __shfl_xor(aw, 32);

    float4 bv = ((const float4*)bias)[fl];
    float ox = fmaxf(ax + bv.x, 0.f);
    float oy = fmaxf(ay + bv.y, 0.f);
    float oz = fmaxf(az + bv.z, 0.f);
    float ow = fmaxf(aw + bv.w, 0.f);

    if (sub == 0) {
        if (writeHalf) {
            __half2 p0 = __floats2half2_rn(ox, oy);
            __half2 p1 = __floats2half2_rn(oz, ow);
            uint2 pk;
            pk.x = *(unsigned int*)&p0;
            pk.y = *(unsigned int*)&p1;
            ((uint2*)YH)[(size_t)v * 32 + fl] = pk;
        } else {
            ((float4*)YF)[(size_t)v * 32 + fl] = make_float4(ox, oy, oz, ow);
        }
    }
}

// ---------------- launch ----------------

extern "C" void kernel_launch(void* const* d_in, const int* in_sizes, int n_in,
                              void* d_out, int out_size, void* d_ws, size_t ws_size,
                              hipStream_t stream) {
    const float* x = (const float*)d_in[0];
    const int* ei = (const int*)d_in[1];
    const float* W = (const float*)d_in[2];
    const float* b = (const float*)d_in[3];
    float* out = (float*)d_out;

    const int N = in_sizes[0] / D;       // 50000
    const int E = in_sizes[1] / 2;       // 800000

    const int* src = ei;
    const int* dst = ei + E;

    int* wsi = (int*)d_ws;
    float* wsf = (float*)d_ws;
    const size_t o_deg  = 0;                 // N ints (memset 0)
    const size_t o_dinv = o_deg + 50000;     // N floats
    const size_t o_rp   = o_dinv + 50000;    // N+1 ints (pad 50016)
    const size_t o_part = o_rp + 50016;      // 256
    const size_t o_boff = o_part + 256;      // 256 -> ends 150528 (8B-aligned)
    const size_t o_rank = o_boff + 256;      // E ints
    const size_t o_rec  = o_rank + 800000;   // E int2
    const size_t o_h    = o_rec + 1600000;   // N*128 halves = 3.2M words
    const size_t o_wht  = o_h + 3200000;     // 2*128*128 halves = 16384 words
    const size_t o_y1h  = o_wht + 16384;     // N*128 halves

    int* degInt  = wsi + o_deg;
    float* dinv  = wsf + o_dinv;
    int* row_ptr = wsi + o_rp;
    int* partial = wsi + o_part;
    int* blockoff= wsi + o_boff;
    int* rank    = wsi + o_rank;
    int2* recs   = (int2*)(wsi + o_rec);
    __half* h    = (__half*)(wsi + o_h);
    __half* wht  = (__half*)(wsi + o_wht);
    __half* y1h  = (__half*)(wsi + o_y1h);

    const int nb_e = (E + 255) / 256;           // 3125
    const int nb_s = (N + SCAN_B - 1) / SCAN_B; // 196

    hipMemsetAsync(degInt, 0, (size_t)50000 * sizeof(int), stream);
    count_kernel<<<nb_e, 256, 0, stream>>>(dst, degInt, rank, E);
    scanA_kernel<<<nb_s, SCAN_B, 0, stream>>>(degInt, partial, N);
    scanB_kernel<<<1, 256, 0, stream>>>(partial, blockoff, nb_s);
    scanC_kernel<<<nb_s, SCAN_B, 0, stream>>>(degInt, blockoff, row_ptr, dinv, N, nb_s);
    fill_kernel<<<nb_e, 256, 0, stream>>>(src, dst, rank, row_ptr, dinv, recs, E);
    cvtw_kernel<<<128, 256, 0, stream>>>(W, wht);

    const int nb_gemm = (N + 63) / 64;   // 782
    const int nb_agg  = (N + 3) / 4;     // 12500

    gemm_mfma_kernel<<<nb_gemm, 256, 0, stream>>>(x, nullptr, wht, h, N, 1);
    agg_kernel<<<nb_agg, 256, 0, stream>>>(h, recs, row_ptr, dinv, b, nullptr, y1h, N, 1);
    gemm_mfma_kernel<<<nb_gemm, 256, 0, stream>>>(nullptr, y1h, wht + 16384, h, N, 0);
    agg_kernel<<<nb_agg, 256, 0, stream>>>(h, recs, row_ptr, dinv, b + D, out, nullptr, N, 0);
}